// Round 1
// baseline (128.931 us; speedup 1.0000x reference)
//
#include <hip/hip_runtime.h>

// Problem constants (LaplacianReg): B=32, V=65536, K=8, C=3, all fp32.
#define BB 32
#define VV 65536
#define KK 8
#define CC 3

constexpr int TV   = 64;          // v-tile per block
constexpr int ROW  = BB * CC;     // 96 floats per transposed v-row
constexpr int PROW = ROW + 1;     // 97: LDS pad (96 % 32 == 0 would be 21-way conflict)
constexpr int TILE_ELEMS = TV * ROW;  // 6144 floats per tile

// ---------------------------------------------------------------------------
// Pass 1: d_t[v*96 + b*3 + c] = out[(b*V+v)*3+c] - tgt[(b*V+v)*3+c]
// Fully coalesced on both sides via LDS tile transpose.
// ---------------------------------------------------------------------------
__global__ __launch_bounds__(256) void lap_pass1_transpose_sub(
    const float* __restrict__ outp, const float* __restrict__ tgtp,
    float* __restrict__ dt) {
  __shared__ float tile[TV * PROW];   // 24.8 KB
  const int t  = threadIdx.x;
  const int v0 = blockIdx.x * TV;

  // Load+subtract: element (b, j) with j in [0,192) covering (vrel, c).
  // Global address = b*V*3 + v0*3 + j  (contiguous in j -> coalesced float4).
  const float4* o4 = (const float4*)outp;
  const float4* t4 = (const float4*)tgtp;
  const int src_base4 = (v0 * CC) >> 2;           // v0*3/4, v0 mult of 64 -> exact
  #pragma unroll
  for (int l4 = t; l4 < TILE_ELEMS / 4; l4 += 256) {
    int b  = l4 / (TV * CC / 4);                  // 48 float4 per b
    int j4 = l4 - b * (TV * CC / 4);
    int src = b * (VV * CC / 4) + src_base4 + j4;
    float4 a = o4[src];
    float4 g = t4[src];
    float dv[4] = {a.x - g.x, a.y - g.y, a.z - g.z, a.w - g.w};
    int j = 4 * j4;
    #pragma unroll
    for (int q = 0; q < 4; q++) {
      int jj = j + q;
      int vrel = jj / CC, c = jj - vrel * CC;
      tile[vrel * PROW + b * CC + c] = dv[q];
    }
  }
  __syncthreads();

  // Store: d_t region for this tile is 6144 contiguous floats.
  float4* dst4 = (float4*)(dt + v0 * ROW);        // v0*96, 16B-aligned
  #pragma unroll
  for (int l4 = t; l4 < TILE_ELEMS / 4; l4 += 256) {
    int e = 4 * l4;
    int vrel = e / ROW, r = e - vrel * ROW;       // 4 | 96 -> never crosses a row
    const float* p = &tile[vrel * PROW + r];
    dst4[l4] = make_float4(p[0], p[1], p[2], p[3]);
  }
}

// ---------------------------------------------------------------------------
// Pass 2: res[b,v,c] = ( d_t[v][b][c] + sum_k w[v,k]*d_t[idx[v,k]][b][c] )^2
// 32-lane group per v: lane = b, 3 channels per lane. Gathers are contiguous
// 384 B rows (all bytes used). Output restaged via LDS for coalesced writes.
// ---------------------------------------------------------------------------
__global__ __launch_bounds__(256) void lap_pass2_gather(
    const float* __restrict__ dt, const int* __restrict__ nidx,
    const float* __restrict__ nw, float* __restrict__ res) {
  __shared__ float rtile[TV * PROW];  // 24.8 KB
  __shared__ int   idx_s[TV * KK];    // 2 KB
  __shared__ float w_s[TV * KK];      // 2 KB
  const int t  = threadIdx.x;
  const int v0 = blockIdx.x * TV;

  // Stage idx/w for the 64 v's (coalesced).
  #pragma unroll
  for (int l = t; l < TV * KK; l += 256) {
    idx_s[l] = nidx[v0 * KK + l];
    w_s[l]   = nw[v0 * KK + l];
  }
  __syncthreads();

  const int g    = t >> 5;   // v-group 0..7
  const int lane = t & 31;   // = b
  #pragma unroll
  for (int i = 0; i < TV / 8; i++) {
    const int vrel = i * 8 + g;
    const int v    = v0 + vrel;
    // self term
    const float* self = dt + v * ROW + lane * CC;
    float ax = self[0], ay = self[1], az = self[2];
    #pragma unroll
    for (int k = 0; k < KK; k++) {
      const int   nb = idx_s[vrel * KK + k];   // LDS broadcast within group
      const float wt = w_s[vrel * KK + k];
      const float* p = dt + nb * ROW + lane * CC;  // contiguous 384B row / group
      ax = fmaf(wt, p[0], ax);
      ay = fmaf(wt, p[1], ay);
      az = fmaf(wt, p[2], az);
    }
    float* rp = &rtile[vrel * PROW + lane * CC];
    rp[0] = ax * ax; rp[1] = ay * ay; rp[2] = az * az;
  }
  __syncthreads();

  // Coalesced writeback to (B,V,C): res[b*V*3 + v0*3 + j], j in [0,192).
  float4* r4 = (float4*)res;
  const int dst_base4 = (v0 * CC) >> 2;
  #pragma unroll
  for (int l4 = t; l4 < TILE_ELEMS / 4; l4 += 256) {
    int b  = l4 / (TV * CC / 4);
    int j4 = l4 - b * (TV * CC / 4);
    int j  = 4 * j4;
    float tmp[4];
    #pragma unroll
    for (int q = 0; q < 4; q++) {
      int jj = j + q;
      int vrel = jj / CC, c = jj - vrel * CC;
      tmp[q] = rtile[vrel * PROW + b * CC + c];
    }
    r4[b * (VV * CC / 4) + dst_base4 + j4] = make_float4(tmp[0], tmp[1], tmp[2], tmp[3]);
  }
}

// ---------------------------------------------------------------------------
// Fallback (ws too small): fused direct kernel, one thread per (b,v).
// Slower (scattered 12B gathers) but correct with zero workspace.
// ---------------------------------------------------------------------------
__global__ __launch_bounds__(256) void lap_fused_fallback(
    const float* __restrict__ outp, const float* __restrict__ tgtp,
    const int* __restrict__ nidx, const float* __restrict__ nw,
    float* __restrict__ res) {
  int tid = blockIdx.x * 256 + threadIdx.x;   // tid = b*V + v
  if (tid >= BB * VV) return;
  int v = tid & (VV - 1);
  int b = tid >> 16;
  float ax = 0.f, ay = 0.f, az = 0.f;
  #pragma unroll
  for (int k = 0; k < KK; k++) {
    int   nb = nidx[v * KK + k];
    float wt = nw[v * KK + k];
    const float* po = outp + (b * VV + nb) * CC;
    const float* pt = tgtp + (b * VV + nb) * CC;
    ax = fmaf(wt, po[0] - pt[0], ax);
    ay = fmaf(wt, po[1] - pt[1], ay);
    az = fmaf(wt, po[2] - pt[2], az);
  }
  const float* so = outp + tid * CC;
  const float* st = tgtp + tid * CC;
  float dx = so[0] - st[0] + ax;
  float dy = so[1] - st[1] + ay;
  float dz = so[2] - st[2] + az;
  float* rp = res + tid * CC;
  rp[0] = dx * dx; rp[1] = dy * dy; rp[2] = dz * dz;
}

extern "C" void kernel_launch(void* const* d_in, const int* in_sizes, int n_in,
                              void* d_out, int out_size, void* d_ws, size_t ws_size,
                              hipStream_t stream) {
  const float* outp = (const float*)d_in[0];
  const float* tgtp = (const float*)d_in[1];
  const int*   nidx = (const int*)d_in[2];
  const float* nw   = (const float*)d_in[3];
  float* res = (float*)d_out;

  const size_t dt_bytes = (size_t)VV * ROW * sizeof(float);  // 25.2 MB
  if (ws_size >= dt_bytes) {
    float* dt = (float*)d_ws;
    lap_pass1_transpose_sub<<<VV / TV, 256, 0, stream>>>(outp, tgtp, dt);
    lap_pass2_gather<<<VV / TV, 256, 0, stream>>>(dt, nidx, nw, res);
  } else {
    lap_fused_fallback<<<(BB * VV) / 256, 256, 0, stream>>>(outp, tgtp, nidx, nw, res);
  }
}

// Round 2
// 114.039 us; speedup vs baseline: 1.1306x; 1.1306x over previous
//
#include <hip/hip_runtime.h>

// LaplacianReg: B=32, V=65536, K=8, C=3, fp32 in/out.
// res[b,v,c] = ( d[b,v,c] + sum_k w[v,k]*d[b,idx[v,k],c] )^2,  d = out - tgt
// Strategy: transpose d to bf16 (v, b, c) rows of 192B so one neighbor gather
// serves all 32 batches x 3 channels; compute fp32; coalesced fp32 output.
#define BB 32
#define VV 65536
#define KK 8
#define CC 3

constexpr int TV   = 64;              // v-tile per block
constexpr int ROW  = BB * CC;         // 96 elems per transposed v-row
constexpr int PROW = ROW + 1;         // LDS pad
constexpr int TILE_ELEMS = TV * ROW;  // 6144
constexpr int ROWU = ROW / 2;         // 48 uints per bf16 row (192B)

__device__ __forceinline__ unsigned int f2bf(float f) {
  unsigned int u = __float_as_uint(f);
  u += 0x7FFFu + ((u >> 16) & 1u);    // round-to-nearest-even
  return u >> 16;
}
__device__ __forceinline__ float bflo(unsigned int u) { return __uint_as_float(u << 16); }
__device__ __forceinline__ float bfhi(unsigned int u) { return __uint_as_float(u & 0xFFFF0000u); }

// ---------------------------------------------------------------------------
// Pass 1: dt[v][b][c] = bf16(out[b,v,c] - tgt[b,v,c]), via LDS tile transpose.
// Coalesced float4 reads, coalesced uint4 (8x bf16) writes.
// ---------------------------------------------------------------------------
__global__ __launch_bounds__(256) void lap_pass1_transpose_sub(
    const float* __restrict__ outp, const float* __restrict__ tgtp,
    unsigned int* __restrict__ dt) {
  __shared__ float tile[TV * PROW];   // 24.8 KB
  const int t  = threadIdx.x;
  const int v0 = blockIdx.x * TV;

  const float4* o4 = (const float4*)outp;
  const float4* t4 = (const float4*)tgtp;
  const int src_base4 = (v0 * CC) >> 2;           // exact: v0 multiple of 64
  #pragma unroll
  for (int l4 = t; l4 < TILE_ELEMS / 4; l4 += 256) {
    int b  = l4 / (TV * CC / 4);                  // 48 float4 per b
    int j4 = l4 - b * (TV * CC / 4);
    int src = b * (VV * CC / 4) + src_base4 + j4;
    float4 a = o4[src];
    float4 g = t4[src];
    float dv[4] = {a.x - g.x, a.y - g.y, a.z - g.z, a.w - g.w};
    int j = 4 * j4;
    #pragma unroll
    for (int q = 0; q < 4; q++) {
      int jj = j + q;
      int vrel = jj / CC, c = jj - vrel * CC;
      tile[vrel * PROW + b * CC + c] = dv[q];
    }
  }
  __syncthreads();

  // Pack 8 consecutive elems -> uint4 of bf16 pairs. 8 | 96, never crosses rows.
  uint4* dst = (uint4*)(dt + (size_t)v0 * ROWU);  // byte offset v0*192, 16B aligned
  #pragma unroll
  for (int i8 = t; i8 < TILE_ELEMS / 8; i8 += 256) {
    int e = i8 * 8;
    int vrel = e / ROW, r = e - vrel * ROW;
    const float* p = &tile[vrel * PROW + r];
    uint4 o;
    o.x = f2bf(p[0]) | (f2bf(p[1]) << 16);
    o.y = f2bf(p[2]) | (f2bf(p[3]) << 16);
    o.z = f2bf(p[4]) | (f2bf(p[5]) << 16);
    o.w = f2bf(p[6]) | (f2bf(p[7]) << 16);
    dst[i8] = o;
  }
}

// ---------------------------------------------------------------------------
// Pass 2: 16-lane group per v, lane l covers batches 2l,2l+1 (6 bf16 = 3 uints
// = one dwordx3 per gather row). Gather rows are contiguous 192B. Output
// restaged via LDS for coalesced fp32 float4 writes in (B,V,C).
// ---------------------------------------------------------------------------
__global__ __launch_bounds__(256) void lap_pass2_gather(
    const unsigned int* __restrict__ dt, const int* __restrict__ nidx,
    const float* __restrict__ nw, float* __restrict__ res) {
  __shared__ float rtile[TV * PROW];  // 24.8 KB
  __shared__ int   idx_s[TV * KK];    // 2 KB
  __shared__ float w_s[TV * KK];      // 2 KB
  const int t  = threadIdx.x;
  const int v0 = blockIdx.x * TV;

  for (int l = t; l < TV * KK; l += 256) {
    idx_s[l] = nidx[v0 * KK + l];
    w_s[l]   = nw[v0 * KK + l];
  }
  __syncthreads();

  const int g = t >> 4;   // 16 groups per block
  const int l = t & 15;   // lane within group; covers b = 2l, 2l+1
  #pragma unroll 2
  for (int i = 0; i < TV / 16; i++) {
    const int vrel = i * 16 + g;
    const int v    = v0 + vrel;

    // Preload this v's 8 idx + 8 w via 2x b128 each (broadcast within group).
    const int4*   ip = (const int4*)&idx_s[vrel * KK];
    const float4* wp = (const float4*)&w_s[vrel * KK];
    int4   ia = ip[0], ib = ip[1];
    float4 wa = wp[0], wb = wp[1];
    int   nbk[KK] = {ia.x, ia.y, ia.z, ia.w, ib.x, ib.y, ib.z, ib.w};
    float wk[KK]  = {wa.x, wa.y, wa.z, wa.w, wb.x, wb.y, wb.z, wb.w};

    // self term
    const unsigned int* sp = dt + (size_t)v * ROWU + 3 * l;
    unsigned int s0 = sp[0], s1 = sp[1], s2 = sp[2];
    float x0 = bflo(s0), y0 = bfhi(s0), z0 = bflo(s1);
    float x1 = bfhi(s1), y1 = bflo(s2), z1 = bfhi(s2);

    #pragma unroll
    for (int k = 0; k < KK; k++) {
      const unsigned int* p = dt + (size_t)nbk[k] * ROWU + 3 * l;
      unsigned int u0 = p[0], u1 = p[1], u2 = p[2];
      const float wt = wk[k];
      x0 = fmaf(wt, bflo(u0), x0);
      y0 = fmaf(wt, bfhi(u0), y0);
      z0 = fmaf(wt, bflo(u1), z0);
      x1 = fmaf(wt, bfhi(u1), x1);
      y1 = fmaf(wt, bflo(u2), y1);
      z1 = fmaf(wt, bfhi(u2), z1);
    }
    float* rp = &rtile[vrel * PROW + 6 * l];  // elems 6l..6l+5 = (b=2l,c0..2),(b=2l+1,c0..2)
    rp[0] = x0 * x0; rp[1] = y0 * y0; rp[2] = z0 * z0;
    rp[3] = x1 * x1; rp[4] = y1 * y1; rp[5] = z1 * z1;
  }
  __syncthreads();

  // Coalesced writeback to (B,V,C).
  float4* r4 = (float4*)res;
  const int dst_base4 = (v0 * CC) >> 2;
  #pragma unroll
  for (int l4 = t; l4 < TILE_ELEMS / 4; l4 += 256) {
    int b  = l4 / (TV * CC / 4);
    int j4 = l4 - b * (TV * CC / 4);
    int j  = 4 * j4;
    float tmp[4];
    #pragma unroll
    for (int q = 0; q < 4; q++) {
      int jj = j + q;
      int vrel = jj / CC, c = jj - vrel * CC;
      tmp[q] = rtile[vrel * PROW + b * CC + c];
    }
    r4[b * (VV * CC / 4) + dst_base4 + j4] = make_float4(tmp[0], tmp[1], tmp[2], tmp[3]);
  }
}

// ---------------------------------------------------------------------------
// Fallback (ws too small): fused fp32 direct kernel, one thread per (b,v).
// ---------------------------------------------------------------------------
__global__ __launch_bounds__(256) void lap_fused_fallback(
    const float* __restrict__ outp, const float* __restrict__ tgtp,
    const int* __restrict__ nidx, const float* __restrict__ nw,
    float* __restrict__ res) {
  int tid = blockIdx.x * 256 + threadIdx.x;
  if (tid >= BB * VV) return;
  int v = tid & (VV - 1);
  int b = tid >> 16;
  float ax = 0.f, ay = 0.f, az = 0.f;
  #pragma unroll
  for (int k = 0; k < KK; k++) {
    int   nb = nidx[v * KK + k];
    float wt = nw[v * KK + k];
    const float* po = outp + ((size_t)b * VV + nb) * CC;
    const float* pt = tgtp + ((size_t)b * VV + nb) * CC;
    ax = fmaf(wt, po[0] - pt[0], ax);
    ay = fmaf(wt, po[1] - pt[1], ay);
    az = fmaf(wt, po[2] - pt[2], az);
  }
  const float* so = outp + (size_t)tid * CC;
  const float* st = tgtp + (size_t)tid * CC;
  float dx = so[0] - st[0] + ax;
  float dy = so[1] - st[1] + ay;
  float dz = so[2] - st[2] + az;
  float* rp = res + (size_t)tid * CC;
  rp[0] = dx * dx; rp[1] = dy * dy; rp[2] = dz * dz;
}

extern "C" void kernel_launch(void* const* d_in, const int* in_sizes, int n_in,
                              void* d_out, int out_size, void* d_ws, size_t ws_size,
                              hipStream_t stream) {
  const float* outp = (const float*)d_in[0];
  const float* tgtp = (const float*)d_in[1];
  const int*   nidx = (const int*)d_in[2];
  const float* nw   = (const float*)d_in[3];
  float* res = (float*)d_out;

  const size_t dt_bytes = (size_t)VV * ROW * 2;   // 12.6 MB bf16
  if (ws_size >= dt_bytes) {
    unsigned int* dt = (unsigned int*)d_ws;
    lap_pass1_transpose_sub<<<VV / TV, 256, 0, stream>>>(outp, tgtp, dt);
    lap_pass2_gather<<<VV / TV, 256, 0, stream>>>(dt, nidx, nw, res);
  } else {
    lap_fused_fallback<<<(BB * VV) / 256, 256, 0, stream>>>(outp, tgtp, nidx, nw, res);
  }
}